// Round 1
// baseline (2114.306 us; speedup 1.0000x reference)
//
#include <hip/hip_runtime.h>

#define BB 2
#define NN 2048
#define DD 1024
#define HH 16
#define HD 64
#define RR (BB * NN)  // 4096 rows

__device__ __forceinline__ float sigmoidf_(float x) { return 1.f / (1.f + __expf(-x)); }

// ---------------------------------------------------------------------------
// Generic fp32 tiled GEMM: C[M,N] = A[M,K] @ B[K,N].
// Requires M%128==0, K%16==0, N%8==0 (guarded for N not multiple of 128).
// 128x128 tile, BK=16, 256 threads, 8x8 micro-tile per thread.
// ---------------------------------------------------------------------------
__global__ __launch_bounds__(256) void gemm_f32(const float* __restrict__ A,
                                                const float* __restrict__ B,
                                                float* __restrict__ C,
                                                int M, int N, int K) {
    __shared__ float As[16][128];  // transposed A tile: As[k][m]
    __shared__ float Bs[16][128];
    const int tid = threadIdx.x;
    const int bm = blockIdx.y * 128;
    const int bn = blockIdx.x * 128;
    const int tx = tid & 15, ty = tid >> 4;
    const int arow = tid >> 1, ak0 = (tid & 1) * 8;
    const int brow = tid >> 4, bn0 = (tid & 15) * 8;

    float acc[8][8];
#pragma unroll
    for (int i = 0; i < 8; i++)
#pragma unroll
        for (int j = 0; j < 8; j++) acc[i][j] = 0.f;

    for (int kb = 0; kb < K; kb += 16) {
        const float* ap = A + (size_t)(bm + arow) * K + kb + ak0;
        float4 a0 = *(const float4*)(ap);
        float4 a1 = *(const float4*)(ap + 4);
        const int gn = bn + bn0;
        float4 b0 = make_float4(0.f, 0.f, 0.f, 0.f), b1 = b0;
        if (gn < N) {
            const float* bp = B + (size_t)(kb + brow) * N + gn;
            b0 = *(const float4*)(bp);
            b1 = *(const float4*)(bp + 4);
        }
        __syncthreads();
        As[ak0 + 0][arow] = a0.x; As[ak0 + 1][arow] = a0.y;
        As[ak0 + 2][arow] = a0.z; As[ak0 + 3][arow] = a0.w;
        As[ak0 + 4][arow] = a1.x; As[ak0 + 5][arow] = a1.y;
        As[ak0 + 6][arow] = a1.z; As[ak0 + 7][arow] = a1.w;
        *(float4*)&Bs[brow][bn0] = b0;
        *(float4*)&Bs[brow][bn0 + 4] = b1;
        __syncthreads();
#pragma unroll
        for (int kk = 0; kk < 16; kk++) {
            float4 x0 = *(const float4*)&As[kk][ty * 8];
            float4 x1 = *(const float4*)&As[kk][ty * 8 + 4];
            float4 y0 = *(const float4*)&Bs[kk][tx * 8];
            float4 y1 = *(const float4*)&Bs[kk][tx * 8 + 4];
            float xa[8] = {x0.x, x0.y, x0.z, x0.w, x1.x, x1.y, x1.z, x1.w};
            float yb[8] = {y0.x, y0.y, y0.z, y0.w, y1.x, y1.y, y1.z, y1.w};
#pragma unroll
            for (int i = 0; i < 8; i++)
#pragma unroll
                for (int j = 0; j < 8; j++) acc[i][j] += xa[i] * yb[j];
        }
    }
    const int cn = bn + tx * 8;
    if (cn < N) {
#pragma unroll
        for (int i = 0; i < 8; i++) {
            float* cp = C + (size_t)(bm + ty * 8 + i) * N + cn;
            *(float4*)cp = make_float4(acc[i][0], acc[i][1], acc[i][2], acc[i][3]);
            *(float4*)(cp + 4) = make_float4(acc[i][4], acc[i][5], acc[i][6], acc[i][7]);
        }
    }
}

// ---------------------------------------------------------------------------
// Post-projection elementwise: silu(q), silu(v), l2norm(silu(k)) per head,
// a = k * gamma * sigmoid(f), lfb = log_sigmoid(f). One wave per (row, head).
// ---------------------------------------------------------------------------
__global__ __launch_bounds__(256) void prep_kernel(float* qb, float* kb, float* vb, float* ab,
                                                   const float* __restrict__ fraw,
                                                   const float* __restrict__ graw,
                                                   float* lfb) {
    const int tid = threadIdx.x;
    const int wav = tid >> 6, lane = tid & 63;
    const int gid = blockIdx.x * 4 + wav;  // (r,h)
    const int r = gid >> 4, h = gid & 15;
    const size_t idx = (size_t)r * DD + (size_t)h * HD + lane;

    float xq = qb[idx], xk = kb[idx], xv = vb[idx];
    float q = xq * sigmoidf_(xq);
    float v = xv * sigmoidf_(xv);
    float kk = xk * sigmoidf_(xk);
    float ss = kk * kk;
#pragma unroll
    for (int m = 1; m <= 32; m <<= 1) ss += __shfl_xor(ss, m);
    float norm = fmaxf(sqrtf(ss), 1e-12f);
    float kn = kk / norm;

    float f = fraw[(size_t)r * HH + h];
    float lf = fminf(f, 0.f) - log1pf(__expf(-fabsf(f)));  // log_sigmoid(f)
    float sig = __expf(lf);                                 // sigmoid(f) = exp(gk)
    float gm = -sigmoidf_(graw[(size_t)r * HH + h]);        // gamma

    qb[idx] = q;
    vb[idx] = v;
    kb[idx] = kn;
    ab[idx] = kn * (gm * sig);
    if (lane == 0) lfb[(size_t)r * HH + h] = lf;
}

__device__ __forceinline__ void load_frag(const float* __restrict__ qb,
                                          const float* __restrict__ kb,
                                          const float* __restrict__ ab,
                                          const float* __restrict__ lfb,
                                          const float* __restrict__ vob,
                                          size_t base, size_t lfoff, int kq, int v,
                                          float4* a4, float4* k4, float4* q4,
                                          float& vt, float& lf) {
    const float4* ap = (const float4*)(ab + base) + kq * 4;
    const float4* kp = (const float4*)(kb + base) + kq * 4;
    const float4* qp = (const float4*)(qb + base) + kq * 4;
#pragma unroll
    for (int j = 0; j < 4; j++) { a4[j] = ap[j]; k4[j] = kp[j]; q4[j] = qp[j]; }
    vt = vob[base + v];
    lf = lfb[lfoff];
}

// ---------------------------------------------------------------------------
// Sequential delta-rule scan. One wave per (b,h,v-slice of 16): 128 blocks x 64.
// Lane = (kq in 0..3) x (vloc in 0..15). S[k][v] lives in 16 VGPRs per lane.
// u/o reductions over kq via shfl_xor(16/32). No LDS, no barriers.
// o is written in place over v (vob): each wave only touches its own columns.
// ---------------------------------------------------------------------------
__global__ __launch_bounds__(64) void scan_kernel(const float* __restrict__ qb,
                                                  const float* __restrict__ kb,
                                                  const float* __restrict__ ab,
                                                  const float* __restrict__ lfb,
                                                  float* vob) {
    const int bx = blockIdx.x;    // 0..127
    const int bh = bx >> 2;       // (b,h)
    const int wslice = bx & 3;    // v-slice
    const int b = bh >> 4, h = bh & 15;
    const int lane = threadIdx.x;
    const int kq = lane >> 4;
    const int vloc = lane & 15;
    const int v = wslice * 16 + vloc;

    const size_t base0 = (size_t)(b * NN) * DD + (size_t)h * HD;
    const size_t lf0 = (size_t)(b * NN) * HH + h;

    float S[16];
#pragma unroll
    for (int i = 0; i < 16; i++) S[i] = 0.f;

    float4 A[2][4], K[2][4], Q[2][4];
    float VT[2], LF[2];
    load_frag(qb, kb, ab, lfb, vob, base0, lf0, kq, v, A[0], K[0], Q[0], VT[0], LF[0]);
    load_frag(qb, kb, ab, lfb, vob, base0 + DD, lf0 + HH, kq, v, A[1], K[1], Q[1], VT[1], LF[1]);

#pragma unroll 2
    for (int t = 0; t < NN; t++) {
        const int cb = t & 1;
        const float lam = __expf(LF[cb]);
        float pu = 0.f;
#pragma unroll
        for (int j = 0; j < 4; j++) {
            pu += A[cb][j].x * S[4 * j + 0] + A[cb][j].y * S[4 * j + 1] +
                  A[cb][j].z * S[4 * j + 2] + A[cb][j].w * S[4 * j + 3];
        }
        pu += __shfl_xor(pu, 16);
        pu += __shfl_xor(pu, 32);
        const float u = lam * pu + VT[cb];
        float po = 0.f;
#pragma unroll
        for (int j = 0; j < 4; j++) {
            S[4 * j + 0] = lam * S[4 * j + 0] + K[cb][j].x * u; po += Q[cb][j].x * S[4 * j + 0];
            S[4 * j + 1] = lam * S[4 * j + 1] + K[cb][j].y * u; po += Q[cb][j].y * S[4 * j + 1];
            S[4 * j + 2] = lam * S[4 * j + 2] + K[cb][j].z * u; po += Q[cb][j].z * S[4 * j + 2];
            S[4 * j + 3] = lam * S[4 * j + 3] + K[cb][j].w * u; po += Q[cb][j].w * S[4 * j + 3];
        }
        po += __shfl_xor(po, 16);
        po += __shfl_xor(po, 32);
        if (lane < 16) vob[base0 + (size_t)t * DD + wslice * 16 + lane] = po;
        // prefetch t+2 into the buffer just consumed (1 full iteration of slack)
        const int tn = (t + 2 < NN) ? t + 2 : NN - 1;
        load_frag(qb, kb, ab, lfb, vob, base0 + (size_t)tn * DD, lf0 + (size_t)tn * HH,
                  kq, v, A[cb], K[cb], Q[cb], VT[cb], LF[cb]);
    }
}

// ---------------------------------------------------------------------------
// out = LayerNorm(o * sigmoid(gatep)) * norm_w, in place over vob. One block/row.
// ---------------------------------------------------------------------------
__global__ __launch_bounds__(256) void gate_ln_kernel(float* vob,
                                                      const float* __restrict__ gatep,
                                                      const float* __restrict__ nw) {
    const int r = blockIdx.x, tid = threadIdx.x;
    const int wav = tid >> 6, lane = tid & 63;
    __shared__ float red[8];
    const size_t rb = (size_t)r * DD;

    float vals[4];
    float s = 0.f;
#pragma unroll
    for (int p = 0; p < 4; p++) {
        const int j = tid + 256 * p;
        float xg = vob[rb + j] * sigmoidf_(gatep[rb + j]);
        vals[p] = xg;
        s += xg;
    }
#pragma unroll
    for (int m = 1; m <= 32; m <<= 1) s += __shfl_xor(s, m);
    if (lane == 0) red[wav] = s;
    __syncthreads();
    const float mu = (red[0] + red[1] + red[2] + red[3]) * (1.f / 1024.f);

    float s2 = 0.f;
#pragma unroll
    for (int p = 0; p < 4; p++) { float d = vals[p] - mu; s2 += d * d; }
#pragma unroll
    for (int m = 1; m <= 32; m <<= 1) s2 += __shfl_xor(s2, m);
    if (lane == 0) red[4 + wav] = s2;
    __syncthreads();
    const float var = (red[4] + red[5] + red[6] + red[7]) * (1.f / 1024.f);
    const float rs = rsqrtf(var + 1e-5f);

#pragma unroll
    for (int p = 0; p < 4; p++) {
        const int j = tid + 256 * p;
        vob[rb + j] = (vals[p] - mu) * rs * nw[j];
    }
}

// ---------------------------------------------------------------------------
extern "C" void kernel_launch(void* const* d_in, const int* in_sizes, int n_in,
                              void* d_out, int out_size, void* d_ws, size_t ws_size,
                              hipStream_t stream) {
    const float* x   = (const float*)d_in[0];
    const float* Wq  = (const float*)d_in[1];
    const float* Wk  = (const float*)d_in[2];
    const float* Wv  = (const float*)d_in[3];
    const float* Wgm = (const float*)d_in[4];  // Wgamma
    const float* Wf  = (const float*)d_in[5];
    const float* Wg1 = (const float*)d_in[6];
    const float* Wg2 = (const float*)d_in[7];
    const float* Wo  = (const float*)d_in[8];
    const float* nw  = (const float*)d_in[9];
    float* out = (float*)d_out;

    float* w = (float*)d_ws;
    float* qb    = w;                   // 4096x1024
    float* kb    = qb + 4194304;
    float* vb    = kb + 4194304;        // v -> o -> ln, in place
    float* ab    = vb + 4194304;
    float* gatep = ab + 4194304;        // 4096x1024
    float* fraw  = gatep + 4194304;     // 4096x16
    float* graw  = fraw + 65536;        // 4096x16
    float* g1    = graw + 65536;        // 4096x64
    float* lfb   = g1 + 262144;         // 4096x16

    dim3 blk(256);
    gemm_f32<<<dim3(8, 32), blk, 0, stream>>>(x, Wq, qb, RR, DD, DD);
    gemm_f32<<<dim3(8, 32), blk, 0, stream>>>(x, Wk, kb, RR, DD, DD);
    gemm_f32<<<dim3(8, 32), blk, 0, stream>>>(x, Wv, vb, RR, DD, DD);
    gemm_f32<<<dim3(1, 32), blk, 0, stream>>>(x, Wgm, graw, RR, HH, DD);
    gemm_f32<<<dim3(1, 32), blk, 0, stream>>>(x, Wf, fraw, RR, HH, DD);
    gemm_f32<<<dim3(1, 32), blk, 0, stream>>>(x, Wg1, g1, RR, HD, DD);
    gemm_f32<<<dim3(8, 32), blk, 0, stream>>>(g1, Wg2, gatep, RR, DD, HD);
    prep_kernel<<<RR * HH / 4, blk, 0, stream>>>(qb, kb, vb, ab, fraw, graw, lfb);
    scan_kernel<<<128, 64, 0, stream>>>(qb, kb, ab, lfb, vb);
    gate_ln_kernel<<<RR, blk, 0, stream>>>(vb, gatep, nw);
    gemm_f32<<<dim3(8, 32), blk, 0, stream>>>(vb, Wo, out, RR, DD, DD);
}

// Round 2
// 2035.332 us; speedup vs baseline: 1.0388x; 1.0388x over previous
//
#include <hip/hip_runtime.h>

#define BB 2
#define NN 2048
#define DD 1024
#define HH 16
#define HD 64
#define RR (BB * NN)  // 4096 rows
#define PF 4          // scan pipeline depth (steps); NN % PF == 0

__device__ __forceinline__ float sigmoidf_(float x) { return 1.f / (1.f + __expf(-x)); }

// ---------------------------------------------------------------------------
// Generic fp32 tiled GEMM: C[M,N] = A[M,K] @ B[K,N].
// 128x128 tile, BK=16, 256 threads, 8x8 micro-tile per thread.
// ---------------------------------------------------------------------------
__global__ __launch_bounds__(256) void gemm_f32(const float* __restrict__ A,
                                                const float* __restrict__ B,
                                                float* __restrict__ C,
                                                int M, int N, int K) {
    __shared__ float As[16][128];  // transposed A tile: As[k][m]
    __shared__ float Bs[16][128];
    const int tid = threadIdx.x;
    const int bm = blockIdx.y * 128;
    const int bn = blockIdx.x * 128;
    const int tx = tid & 15, ty = tid >> 4;
    const int arow = tid >> 1, ak0 = (tid & 1) * 8;
    const int brow = tid >> 4, bn0 = (tid & 15) * 8;

    float acc[8][8];
#pragma unroll
    for (int i = 0; i < 8; i++)
#pragma unroll
        for (int j = 0; j < 8; j++) acc[i][j] = 0.f;

    for (int kb = 0; kb < K; kb += 16) {
        const float* ap = A + (size_t)(bm + arow) * K + kb + ak0;
        float4 a0 = *(const float4*)(ap);
        float4 a1 = *(const float4*)(ap + 4);
        const int gn = bn + bn0;
        float4 b0 = make_float4(0.f, 0.f, 0.f, 0.f), b1 = b0;
        if (gn < N) {
            const float* bp = B + (size_t)(kb + brow) * N + gn;
            b0 = *(const float4*)(bp);
            b1 = *(const float4*)(bp + 4);
        }
        __syncthreads();
        As[ak0 + 0][arow] = a0.x; As[ak0 + 1][arow] = a0.y;
        As[ak0 + 2][arow] = a0.z; As[ak0 + 3][arow] = a0.w;
        As[ak0 + 4][arow] = a1.x; As[ak0 + 5][arow] = a1.y;
        As[ak0 + 6][arow] = a1.z; As[ak0 + 7][arow] = a1.w;
        *(float4*)&Bs[brow][bn0] = b0;
        *(float4*)&Bs[brow][bn0 + 4] = b1;
        __syncthreads();
#pragma unroll
        for (int kk = 0; kk < 16; kk++) {
            float4 x0 = *(const float4*)&As[kk][ty * 8];
            float4 x1 = *(const float4*)&As[kk][ty * 8 + 4];
            float4 y0 = *(const float4*)&Bs[kk][tx * 8];
            float4 y1 = *(const float4*)&Bs[kk][tx * 8 + 4];
            float xa[8] = {x0.x, x0.y, x0.z, x0.w, x1.x, x1.y, x1.z, x1.w};
            float yb[8] = {y0.x, y0.y, y0.z, y0.w, y1.x, y1.y, y1.z, y1.w};
#pragma unroll
            for (int i = 0; i < 8; i++)
#pragma unroll
                for (int j = 0; j < 8; j++) acc[i][j] += xa[i] * yb[j];
        }
    }
    const int cn = bn + tx * 8;
    if (cn < N) {
#pragma unroll
        for (int i = 0; i < 8; i++) {
            float* cp = C + (size_t)(bm + ty * 8 + i) * N + cn;
            *(float4*)cp = make_float4(acc[i][0], acc[i][1], acc[i][2], acc[i][3]);
            *(float4*)(cp + 4) = make_float4(acc[i][4], acc[i][5], acc[i][6], acc[i][7]);
        }
    }
}

// ---------------------------------------------------------------------------
// Post-projection elementwise. One wave per (row, head).
//   q = silu(q); v = silu(v); k = l2norm(silu(k)) per head
//   lfb = sigmoid(f) = lambda  (decay factor, exp(log_sigmoid(f)))
//   ab  = k * gamma * lambda^2  ( = lambda * a  — folds the "Sp" decay so the
//         scan computes u = ab@S + v with no extra multiply on the chain)
// ---------------------------------------------------------------------------
__global__ __launch_bounds__(256) void prep_kernel(float* qb, float* kb, float* vb, float* ab,
                                                   const float* __restrict__ fraw,
                                                   const float* __restrict__ graw,
                                                   float* lfb) {
    const int tid = threadIdx.x;
    const int wav = tid >> 6, lane = tid & 63;
    const int gid = blockIdx.x * 4 + wav;  // (r,h)
    const int r = gid >> 4, h = gid & 15;
    const size_t idx = (size_t)r * DD + (size_t)h * HD + lane;

    float xq = qb[idx], xk = kb[idx], xv = vb[idx];
    float q = xq * sigmoidf_(xq);
    float v = xv * sigmoidf_(xv);
    float kk = xk * sigmoidf_(xk);
    float ss = kk * kk;
#pragma unroll
    for (int m = 1; m <= 32; m <<= 1) ss += __shfl_xor(ss, m);
    float norm = fmaxf(sqrtf(ss), 1e-12f);
    float kn = kk / norm;

    float f = fraw[(size_t)r * HH + h];
    float sig = sigmoidf_(f);                               // lambda = exp(log_sigmoid(f))
    float gm = -sigmoidf_(graw[(size_t)r * HH + h]);        // gamma

    qb[idx] = q;
    vb[idx] = v;
    kb[idx] = kn;
    ab[idx] = kn * (gm * sig * sig);                        // lambda * a_t
    if (lane == 0) lfb[(size_t)r * HH + h] = sig;           // lambda
}

// ---------------------------------------------------------------------------
// Sequential delta-rule scan, software-pipelined PF steps deep in registers.
// One wave per (b,h,v-slice of 16): 128 blocks x 64 threads.
// Lane = (kq in 0..3) x (vloc in 0..15). S[k][v] lives in 16 VGPRs per lane.
// Recurrence (with ab = lambda*a precomputed):
//   u = ab@S + v;  S = lambda*S + k (x) u;  o = q@S
// u/o reductions over kq via shfl_xor(16/32). o written in place over v.
// ---------------------------------------------------------------------------
__global__ __launch_bounds__(64) void scan_kernel(const float* __restrict__ qb,
                                                  const float* __restrict__ kb,
                                                  const float* __restrict__ ab,
                                                  const float* __restrict__ lfb,
                                                  float* vob) {
    const int bx = blockIdx.x;    // 0..127
    const int bh = bx >> 2;       // (b,h)
    const int wslice = bx & 3;    // v-slice
    const int b = bh >> 4, h = bh & 15;
    const int lane = threadIdx.x;
    const int kq = lane >> 4;
    const int vloc = lane & 15;
    const int v = wslice * 16 + vloc;

    const size_t base0 = (size_t)(b * NN) * DD + (size_t)h * HD;
    const size_t lf0 = (size_t)(b * NN) * HH + h;

    float S[16];
#pragma unroll
    for (int i = 0; i < 16; i++) S[i] = 0.f;

    float4 A[PF][4], K[PF][4], Q[PF][4];
    float VT[PF], LM[PF];

    // prologue: fill all PF slots (t = 0..PF-1)
#pragma unroll
    for (int i = 0; i < PF; i++) {
        const size_t base = base0 + (size_t)i * DD;
        const float4* ap = (const float4*)(ab + base) + kq * 4;
        const float4* kp = (const float4*)(kb + base) + kq * 4;
        const float4* qp = (const float4*)(qb + base) + kq * 4;
#pragma unroll
        for (int j = 0; j < 4; j++) { A[i][j] = ap[j]; K[i][j] = kp[j]; Q[i][j] = qp[j]; }
        VT[i] = vob[base + v];
        LM[i] = lfb[lf0 + (size_t)i * HH];
    }

    for (int tc = 0; tc < NN; tc += PF) {
#pragma unroll
        for (int i = 0; i < PF; i++) {
            const int t = tc + i;
            const float lam = LM[i];
            // u = ab@S + v   (ab already carries the lambda factor)
            float pu = 0.f;
#pragma unroll
            for (int j = 0; j < 4; j++) {
                pu += A[i][j].x * S[4 * j + 0] + A[i][j].y * S[4 * j + 1] +
                      A[i][j].z * S[4 * j + 2] + A[i][j].w * S[4 * j + 3];
            }
            pu += __shfl_xor(pu, 16);
            pu += __shfl_xor(pu, 32);
            const float u = pu + VT[i];
            // S = lam*S + k u ;  o = q@S
            float po = 0.f;
#pragma unroll
            for (int j = 0; j < 4; j++) {
                S[4 * j + 0] = lam * S[4 * j + 0] + K[i][j].x * u; po += Q[i][j].x * S[4 * j + 0];
                S[4 * j + 1] = lam * S[4 * j + 1] + K[i][j].y * u; po += Q[i][j].y * S[4 * j + 1];
                S[4 * j + 2] = lam * S[4 * j + 2] + K[i][j].z * u; po += Q[i][j].z * S[4 * j + 2];
                S[4 * j + 3] = lam * S[4 * j + 3] + K[i][j].w * u; po += Q[i][j].w * S[4 * j + 3];
            }
            po += __shfl_xor(po, 16);
            po += __shfl_xor(po, 32);
            if (lane < 16) vob[base0 + (size_t)t * DD + wslice * 16 + lane] = po;
            // refill this slot with step t+PF (clamped; tail reloads are harmless)
            const int tn = (t + PF < NN) ? t + PF : NN - 1;
            const size_t nb = base0 + (size_t)tn * DD;
            const float4* ap = (const float4*)(ab + nb) + kq * 4;
            const float4* kp = (const float4*)(kb + nb) + kq * 4;
            const float4* qp = (const float4*)(qb + nb) + kq * 4;
#pragma unroll
            for (int j = 0; j < 4; j++) { A[i][j] = ap[j]; K[i][j] = kp[j]; Q[i][j] = qp[j]; }
            VT[i] = vob[nb + v];
            LM[i] = lfb[lf0 + (size_t)tn * HH];
        }
    }
}

// ---------------------------------------------------------------------------
// out = LayerNorm(o * sigmoid(gatep)) * norm_w, in place over vob. One block/row.
// ---------------------------------------------------------------------------
__global__ __launch_bounds__(256) void gate_ln_kernel(float* vob,
                                                      const float* __restrict__ gatep,
                                                      const float* __restrict__ nw) {
    const int r = blockIdx.x, tid = threadIdx.x;
    const int wav = tid >> 6, lane = tid & 63;
    __shared__ float red[8];
    const size_t rb = (size_t)r * DD;

    float vals[4];
    float s = 0.f;
#pragma unroll
    for (int p = 0; p < 4; p++) {
        const int j = tid + 256 * p;
        float xg = vob[rb + j] * sigmoidf_(gatep[rb + j]);
        vals[p] = xg;
        s += xg;
    }
#pragma unroll
    for (int m = 1; m <= 32; m <<= 1) s += __shfl_xor(s, m);
    if (lane == 0) red[wav] = s;
    __syncthreads();
    const float mu = (red[0] + red[1] + red[2] + red[3]) * (1.f / 1024.f);

    float s2 = 0.f;
#pragma unroll
    for (int p = 0; p < 4; p++) { float d = vals[p] - mu; s2 += d * d; }
#pragma unroll
    for (int m = 1; m <= 32; m <<= 1) s2 += __shfl_xor(s2, m);
    if (lane == 0) red[4 + wav] = s2;
    __syncthreads();
    const float var = (red[4] + red[5] + red[6] + red[7]) * (1.f / 1024.f);
    const float rs = rsqrtf(var + 1e-5f);

#pragma unroll
    for (int p = 0; p < 4; p++) {
        const int j = tid + 256 * p;
        vob[rb + j] = (vals[p] - mu) * rs * nw[j];
    }
}

// ---------------------------------------------------------------------------
extern "C" void kernel_launch(void* const* d_in, const int* in_sizes, int n_in,
                              void* d_out, int out_size, void* d_ws, size_t ws_size,
                              hipStream_t stream) {
    const float* x   = (const float*)d_in[0];
    const float* Wq  = (const float*)d_in[1];
    const float* Wk  = (const float*)d_in[2];
    const float* Wv  = (const float*)d_in[3];
    const float* Wgm = (const float*)d_in[4];  // Wgamma
    const float* Wf  = (const float*)d_in[5];
    const float* Wg1 = (const float*)d_in[6];
    const float* Wg2 = (const float*)d_in[7];
    const float* Wo  = (const float*)d_in[8];
    const float* nw  = (const float*)d_in[9];
    float* out = (float*)d_out;

    float* w = (float*)d_ws;
    float* qb    = w;                   // 4096x1024
    float* kb    = qb + 4194304;
    float* vb    = kb + 4194304;        // v -> o -> ln, in place
    float* ab    = vb + 4194304;
    float* gatep = ab + 4194304;        // 4096x1024
    float* fraw  = gatep + 4194304;     // 4096x16
    float* graw  = fraw + 65536;        // 4096x16
    float* g1    = graw + 65536;        // 4096x64
    float* lfb   = g1 + 262144;         // 4096x16

    dim3 blk(256);
    gemm_f32<<<dim3(8, 32), blk, 0, stream>>>(x, Wq, qb, RR, DD, DD);
    gemm_f32<<<dim3(8, 32), blk, 0, stream>>>(x, Wk, kb, RR, DD, DD);
    gemm_f32<<<dim3(8, 32), blk, 0, stream>>>(x, Wv, vb, RR, DD, DD);
    gemm_f32<<<dim3(1, 32), blk, 0, stream>>>(x, Wgm, graw, RR, HH, DD);
    gemm_f32<<<dim3(1, 32), blk, 0, stream>>>(x, Wf, fraw, RR, HH, DD);
    gemm_f32<<<dim3(1, 32), blk, 0, stream>>>(x, Wg1, g1, RR, HD, DD);
    gemm_f32<<<dim3(8, 32), blk, 0, stream>>>(g1, Wg2, gatep, RR, DD, HD);
    prep_kernel<<<RR * HH / 4, blk, 0, stream>>>(qb, kb, vb, ab, fraw, graw, lfb);
    scan_kernel<<<128, 64, 0, stream>>>(qb, kb, ab, lfb, vb);
    gate_ln_kernel<<<RR, blk, 0, stream>>>(vb, gatep, nw);
    gemm_f32<<<dim3(8, 32), blk, 0, stream>>>(vb, Wo, out, RR, DD, DD);
}

// Round 3
// 1699.211 us; speedup vs baseline: 1.2443x; 1.1978x over previous
//
#include <hip/hip_runtime.h>

#define BB 2
#define NN 2048
#define DD 1024
#define HH 16
#define HD 64
#define RR (BB * NN)  // 4096 rows
#define PF 4          // scan pipeline depth (steps); NN % PF == 0

typedef __bf16 bf16x8 __attribute__((ext_vector_type(8)));
typedef float f32x4 __attribute__((ext_vector_type(4)));

__device__ __forceinline__ float sigmoidf_(float x) { return 1.f / (1.f + __expf(-x)); }

// ---------------------------------------------------------------------------
// bf16-MFMA GEMM: C[M,N] = A[M,K] @ B[K,N], fp32 in/out, bf16 compute.
// M,N % 128 == 0, K % 32 == 0. 128x128 tile, BK=32, 256 thr = 4 waves,
// each wave a 64x64 quadrant = 4x4 tiles of mfma_f32_16x16x32_bf16.
// fp32 -> bf16 conversion happens during LDS staging (no extra buffers).
// LDS stride 40 bf16 (80 B): 16B-aligned frags, conflict-free b128 reads.
// ---------------------------------------------------------------------------
__global__ __launch_bounds__(256) void gemm_bf16(const float* __restrict__ A,
                                                 const float* __restrict__ B,
                                                 float* __restrict__ C,
                                                 int M, int N, int K) {
    constexpr int LW = 40;  // padded row stride (bf16 elems)
    __shared__ __align__(16) __bf16 As[128 * LW];  // As[m][k]
    __shared__ __align__(16) __bf16 Bs[128 * LW];  // Bs[n][k]  (transposed)
    const int tid = threadIdx.x;
    const int lane = tid & 63;
    const int wave = tid >> 6;
    const int wm = (wave >> 1) * 64, wn = (wave & 1) * 64;
    const int bm = blockIdx.y * 128, bn = blockIdx.x * 128;
    const int l15 = lane & 15, quad = lane >> 4;

    // A staging: thread -> (row ar, k-chunk akc of 16)
    const int ar = tid >> 1, akc = (tid & 1) * 16;
    // B staging: thread -> (col bcol, k-chunk bk0 of 16); global reads coalesced in n
    const int bcol = tid & 127, bk0 = (tid >> 7) * 16;

    f32x4 acc[4][4];
#pragma unroll
    for (int i = 0; i < 4; i++)
#pragma unroll
        for (int j = 0; j < 4; j++) acc[i][j] = (f32x4){0.f, 0.f, 0.f, 0.f};

    for (int kb = 0; kb < K; kb += 32) {
        // global loads (fp32)
        float av[16];
        const float* ap = A + (size_t)(bm + ar) * K + kb + akc;
#pragma unroll
        for (int p = 0; p < 4; p++) {
            float4 t = *(const float4*)(ap + 4 * p);
            av[4 * p + 0] = t.x; av[4 * p + 1] = t.y; av[4 * p + 2] = t.z; av[4 * p + 3] = t.w;
        }
        float bv[16];
        const float* bp = B + (size_t)(kb + bk0) * N + bn + bcol;
#pragma unroll
        for (int p = 0; p < 16; p++) bv[p] = bp[(size_t)p * N];

        __syncthreads();  // previous iteration's LDS reads done
        bf16x8 w0, w1, u0, u1;
#pragma unroll
        for (int p = 0; p < 8; p++) {
            w0[p] = (__bf16)av[p]; w1[p] = (__bf16)av[8 + p];
            u0[p] = (__bf16)bv[p]; u1[p] = (__bf16)bv[8 + p];
        }
        *(bf16x8*)&As[ar * LW + akc] = w0;
        *(bf16x8*)&As[ar * LW + akc + 8] = w1;
        *(bf16x8*)&Bs[bcol * LW + bk0] = u0;
        *(bf16x8*)&Bs[bcol * LW + bk0 + 8] = u1;
        __syncthreads();

        bf16x8 af[4], bfr[4];
#pragma unroll
        for (int i = 0; i < 4; i++)
            af[i] = *(const bf16x8*)&As[(wm + i * 16 + l15) * LW + quad * 8];
#pragma unroll
        for (int j = 0; j < 4; j++)
            bfr[j] = *(const bf16x8*)&Bs[(wn + j * 16 + l15) * LW + quad * 8];
#pragma unroll
        for (int i = 0; i < 4; i++)
#pragma unroll
            for (int j = 0; j < 4; j++)
                acc[i][j] = __builtin_amdgcn_mfma_f32_16x16x32_bf16(af[i], bfr[j], acc[i][j], 0, 0, 0);
    }

    // epilogue: C[row = quad*4 + r][col = l15] per 16x16 tile
#pragma unroll
    for (int i = 0; i < 4; i++) {
#pragma unroll
        for (int r = 0; r < 4; r++) {
            const int row = bm + wm + i * 16 + quad * 4 + r;
            float* cp = C + (size_t)row * N + bn + wn + l15;
#pragma unroll
            for (int j = 0; j < 4; j++) cp[j * 16] = acc[i][j][r];
        }
    }
}

// ---------------------------------------------------------------------------
// Generic fp32 tiled GEMM (for small-N projections): C[M,N] = A[M,K] @ B[K,N].
// ---------------------------------------------------------------------------
__global__ __launch_bounds__(256) void gemm_f32(const float* __restrict__ A,
                                                const float* __restrict__ B,
                                                float* __restrict__ C,
                                                int M, int N, int K) {
    __shared__ float As[16][128];  // transposed A tile: As[k][m]
    __shared__ float Bs[16][128];
    const int tid = threadIdx.x;
    const int bm = blockIdx.y * 128;
    const int bn = blockIdx.x * 128;
    const int tx = tid & 15, ty = tid >> 4;
    const int arow = tid >> 1, ak0 = (tid & 1) * 8;
    const int brow = tid >> 4, bn0 = (tid & 15) * 8;

    float acc[8][8];
#pragma unroll
    for (int i = 0; i < 8; i++)
#pragma unroll
        for (int j = 0; j < 8; j++) acc[i][j] = 0.f;

    for (int kb = 0; kb < K; kb += 16) {
        const float* ap = A + (size_t)(bm + arow) * K + kb + ak0;
        float4 a0 = *(const float4*)(ap);
        float4 a1 = *(const float4*)(ap + 4);
        const int gn = bn + bn0;
        float4 b0 = make_float4(0.f, 0.f, 0.f, 0.f), b1 = b0;
        if (gn < N) {
            const float* bp = B + (size_t)(kb + brow) * N + gn;
            b0 = *(const float4*)(bp);
            b1 = *(const float4*)(bp + 4);
        }
        __syncthreads();
        As[ak0 + 0][arow] = a0.x; As[ak0 + 1][arow] = a0.y;
        As[ak0 + 2][arow] = a0.z; As[ak0 + 3][arow] = a0.w;
        As[ak0 + 4][arow] = a1.x; As[ak0 + 5][arow] = a1.y;
        As[ak0 + 6][arow] = a1.z; As[ak0 + 7][arow] = a1.w;
        *(float4*)&Bs[brow][bn0] = b0;
        *(float4*)&Bs[brow][bn0 + 4] = b1;
        __syncthreads();
#pragma unroll
        for (int kk = 0; kk < 16; kk++) {
            float4 x0 = *(const float4*)&As[kk][ty * 8];
            float4 x1 = *(const float4*)&As[kk][ty * 8 + 4];
            float4 y0 = *(const float4*)&Bs[kk][tx * 8];
            float4 y1 = *(const float4*)&Bs[kk][tx * 8 + 4];
            float xa[8] = {x0.x, x0.y, x0.z, x0.w, x1.x, x1.y, x1.z, x1.w};
            float yb[8] = {y0.x, y0.y, y0.z, y0.w, y1.x, y1.y, y1.z, y1.w};
#pragma unroll
            for (int i = 0; i < 8; i++)
#pragma unroll
                for (int j = 0; j < 8; j++) acc[i][j] += xa[i] * yb[j];
        }
    }
    const int cn = bn + tx * 8;
    if (cn < N) {
#pragma unroll
        for (int i = 0; i < 8; i++) {
            float* cp = C + (size_t)(bm + ty * 8 + i) * N + cn;
            *(float4*)cp = make_float4(acc[i][0], acc[i][1], acc[i][2], acc[i][3]);
            *(float4*)(cp + 4) = make_float4(acc[i][4], acc[i][5], acc[i][6], acc[i][7]);
        }
    }
}

// ---------------------------------------------------------------------------
// Post-projection elementwise. One wave per (row, head).
//   q = silu(q); v = silu(v); k = l2norm(silu(k)) per head
//   lfb = lambda = sigmoid(f) = exp(log_sigmoid(f))
//   csb = gamma * lambda^2   (so scan computes u = csb*(k.S) + v)
// ---------------------------------------------------------------------------
__global__ __launch_bounds__(256) void prep_kernel(float* qb, float* kb, float* vb,
                                                   const float* __restrict__ fraw,
                                                   const float* __restrict__ graw,
                                                   float* lfb, float* csb) {
    const int tid = threadIdx.x;
    const int wav = tid >> 6, lane = tid & 63;
    const int gid = blockIdx.x * 4 + wav;  // (r,h)
    const int r = gid >> 4, h = gid & 15;
    const size_t idx = (size_t)r * DD + (size_t)h * HD + lane;

    float xq = qb[idx], xk = kb[idx], xv = vb[idx];
    float q = xq * sigmoidf_(xq);
    float v = xv * sigmoidf_(xv);
    float kk = xk * sigmoidf_(xk);
    float ss = kk * kk;
#pragma unroll
    for (int m = 1; m <= 32; m <<= 1) ss += __shfl_xor(ss, m);
    float norm = fmaxf(sqrtf(ss), 1e-12f);
    float kn = kk / norm;

    float f = fraw[(size_t)r * HH + h];
    float sig = sigmoidf_(f);                               // lambda
    float gm = -sigmoidf_(graw[(size_t)r * HH + h]);        // gamma

    qb[idx] = q;
    vb[idx] = v;
    kb[idx] = kn;
    if (lane == 0) {
        lfb[(size_t)r * HH + h] = sig;
        csb[(size_t)r * HH + h] = gm * sig * sig;
    }
}

// ---------------------------------------------------------------------------
// Sequential delta-rule scan, software-pipelined PF steps deep in registers.
// One wave per (b,h,v-slice of 16): 128 blocks x 64 threads.
// Lane = (kq in 0..3) x (vloc in 0..15). S[k][v] lives in 16 VGPRs per lane.
//   pu = k.S ;  u = c*pu + v ;  S = lam*S + k u ;  o = q.S
// Output o goes to a SEPARATE restrict bf16 buffer -> no store/load aliasing,
// prefetch loads stay in flight across steps.
// ---------------------------------------------------------------------------
__global__ __launch_bounds__(64) void scan_kernel(const float* __restrict__ qb,
                                                  const float* __restrict__ kb,
                                                  const float* __restrict__ vb,
                                                  const float* __restrict__ lfb,
                                                  const float* __restrict__ csb,
                                                  __bf16* __restrict__ obh) {
    const int bx = blockIdx.x;    // 0..127
    const int bh = bx >> 2;       // (b,h)
    const int wslice = bx & 3;    // v-slice
    const int b = bh >> 4, h = bh & 15;
    const int lane = threadIdx.x;
    const int kq = lane >> 4;
    const int vloc = lane & 15;
    const int v = wslice * 16 + vloc;

    const size_t base0 = (size_t)(b * NN) * DD + (size_t)h * HD;
    const size_t lf0 = (size_t)(b * NN) * HH + h;

    float S[16];
#pragma unroll
    for (int i = 0; i < 16; i++) S[i] = 0.f;

    float4 K[PF][4], Q[PF][4];
    float VT[PF], LM[PF], CS[PF];

    // prologue: fill all PF slots (t = 0..PF-1)
#pragma unroll
    for (int i = 0; i < PF; i++) {
        const size_t base = base0 + (size_t)i * DD;
        const float4* kp = (const float4*)(kb + base) + kq * 4;
        const float4* qp = (const float4*)(qb + base) + kq * 4;
#pragma unroll
        for (int j = 0; j < 4; j++) { K[i][j] = kp[j]; Q[i][j] = qp[j]; }
        VT[i] = vb[base + v];
        LM[i] = lfb[lf0 + (size_t)i * HH];
        CS[i] = csb[lf0 + (size_t)i * HH];
    }

    for (int tc = 0; tc < NN; tc += PF) {
#pragma unroll
        for (int i = 0; i < PF; i++) {
            const int t = tc + i;
            const float lam = LM[i];
            // pu = k.S  (4 parallel depth-4 chains, tree combine)
            float pj[4];
#pragma unroll
            for (int j = 0; j < 4; j++) {
                pj[j] = K[i][j].x * S[4 * j + 0] + K[i][j].y * S[4 * j + 1] +
                        K[i][j].z * S[4 * j + 2] + K[i][j].w * S[4 * j + 3];
            }
            float pu = (pj[0] + pj[1]) + (pj[2] + pj[3]);
            pu += __shfl_xor(pu, 16);
            pu += __shfl_xor(pu, 32);
            const float u = CS[i] * pu + VT[i];
            // S = lam*S + k u ;  po = q.S (tree)
            float oj[4];
#pragma unroll
            for (int j = 0; j < 4; j++) {
                float s0 = lam * S[4 * j + 0] + K[i][j].x * u;
                float s1 = lam * S[4 * j + 1] + K[i][j].y * u;
                float s2 = lam * S[4 * j + 2] + K[i][j].z * u;
                float s3 = lam * S[4 * j + 3] + K[i][j].w * u;
                S[4 * j + 0] = s0; S[4 * j + 1] = s1; S[4 * j + 2] = s2; S[4 * j + 3] = s3;
                oj[j] = Q[i][j].x * s0 + Q[i][j].y * s1 + Q[i][j].z * s2 + Q[i][j].w * s3;
            }
            float po = (oj[0] + oj[1]) + (oj[2] + oj[3]);
            po += __shfl_xor(po, 16);
            po += __shfl_xor(po, 32);
            if (lane < 16) obh[base0 + (size_t)t * DD + wslice * 16 + lane] = (__bf16)po;
            // refill this slot with step t+PF (clamped; tail reloads harmless)
            const int tn = (t + PF < NN) ? t + PF : NN - 1;
            const size_t nb = base0 + (size_t)tn * DD;
            const float4* kp = (const float4*)(kb + nb) + kq * 4;
            const float4* qp = (const float4*)(qb + nb) + kq * 4;
#pragma unroll
            for (int j = 0; j < 4; j++) { K[i][j] = kp[j]; Q[i][j] = qp[j]; }
            VT[i] = vb[nb + v];
            LM[i] = lfb[lf0 + (size_t)tn * HH];
            CS[i] = csb[lf0 + (size_t)tn * HH];
        }
    }
}

// ---------------------------------------------------------------------------
// outp = LayerNorm(o * sigmoid(gatep)) * norm_w. o is bf16, result fp32.
// One block per row.
// ---------------------------------------------------------------------------
__global__ __launch_bounds__(256) void gate_ln_kernel(const __bf16* __restrict__ obh,
                                                      const float* __restrict__ gatep,
                                                      const float* __restrict__ nw,
                                                      float* __restrict__ outp) {
    const int r = blockIdx.x, tid = threadIdx.x;
    const int wav = tid >> 6, lane = tid & 63;
    __shared__ float red[8];
    const size_t rb = (size_t)r * DD;

    float vals[4];
    float s = 0.f;
#pragma unroll
    for (int p = 0; p < 4; p++) {
        const int j = tid + 256 * p;
        float xg = (float)obh[rb + j] * sigmoidf_(gatep[rb + j]);
        vals[p] = xg;
        s += xg;
    }
#pragma unroll
    for (int m = 1; m <= 32; m <<= 1) s += __shfl_xor(s, m);
    if (lane == 0) red[wav] = s;
    __syncthreads();
    const float mu = (red[0] + red[1] + red[2] + red[3]) * (1.f / 1024.f);

    float s2 = 0.f;
#pragma unroll
    for (int p = 0; p < 4; p++) { float d = vals[p] - mu; s2 += d * d; }
#pragma unroll
    for (int m = 1; m <= 32; m <<= 1) s2 += __shfl_xor(s2, m);
    if (lane == 0) red[4 + wav] = s2;
    __syncthreads();
    const float var = (red[4] + red[5] + red[6] + red[7]) * (1.f / 1024.f);
    const float rs = rsqrtf(var + 1e-5f);

#pragma unroll
    for (int p = 0; p < 4; p++) {
        const int j = tid + 256 * p;
        outp[rb + j] = (vals[p] - mu) * rs * nw[j];
    }
}

// ---------------------------------------------------------------------------
extern "C" void kernel_launch(void* const* d_in, const int* in_sizes, int n_in,
                              void* d_out, int out_size, void* d_ws, size_t ws_size,
                              hipStream_t stream) {
    const float* x   = (const float*)d_in[0];
    const float* Wq  = (const float*)d_in[1];
    const float* Wk  = (const float*)d_in[2];
    const float* Wv  = (const float*)d_in[3];
    const float* Wgm = (const float*)d_in[4];  // Wgamma
    const float* Wf  = (const float*)d_in[5];
    const float* Wg1 = (const float*)d_in[6];
    const float* Wg2 = (const float*)d_in[7];
    const float* Wo  = (const float*)d_in[8];
    const float* nw  = (const float*)d_in[9];
    float* out = (float*)d_out;

    float* w = (float*)d_ws;
    float* qb    = w;                   // 4096x1024 f32 (q; later reused for LN output)
    float* kb    = qb + 4194304;        // 4096x1024 f32
    float* vb    = kb + 4194304;        // 4096x1024 f32 (read-only in scan)
    float* gatep = vb + 4194304;        // 4096x1024 f32
    float* fraw  = gatep + 4194304;     // 4096x16
    float* graw  = fraw + 65536;        // 4096x16
    float* g1    = graw + 65536;        // 4096x64
    float* lfb   = g1 + 262144;         // 4096x16 (lambda)
    float* csb   = lfb + 65536;         // 4096x16 (gamma*lambda^2)
    __bf16* obh  = (__bf16*)(csb + 65536);  // 4096x1024 bf16 scan output
    // total ~77.2 MB

    dim3 blk(256);
    gemm_bf16<<<dim3(8, 32), blk, 0, stream>>>(x, Wq, qb, RR, DD, DD);
    gemm_bf16<<<dim3(8, 32), blk, 0, stream>>>(x, Wk, kb, RR, DD, DD);
    gemm_bf16<<<dim3(8, 32), blk, 0, stream>>>(x, Wv, vb, RR, DD, DD);
    gemm_f32<<<dim3(1, 32), blk, 0, stream>>>(x, Wgm, graw, RR, HH, DD);
    gemm_f32<<<dim3(1, 32), blk, 0, stream>>>(x, Wf, fraw, RR, HH, DD);
    gemm_f32<<<dim3(1, 32), blk, 0, stream>>>(x, Wg1, g1, RR, HD, DD);
    gemm_f32<<<dim3(8, 32), blk, 0, stream>>>(g1, Wg2, gatep, RR, DD, HD);
    prep_kernel<<<RR * HH / 4, blk, 0, stream>>>(qb, kb, vb, fraw, graw, lfb, csb);
    scan_kernel<<<128, 64, 0, stream>>>(qb, kb, vb, lfb, csb, obh);
    gate_ln_kernel<<<RR, blk, 0, stream>>>(obh, gatep, nw, qb);
    gemm_bf16<<<dim3(8, 32), blk, 0, stream>>>(qb, Wo, out, RR, DD, DD);
}

// Round 4
// 1375.625 us; speedup vs baseline: 1.5370x; 1.2352x over previous
//
#include <hip/hip_runtime.h>

#define BB 2
#define NN 2048
#define DD 1024
#define HH 16
#define HD 64
#define RR (BB * NN)  // 4096 rows
#define CH 32         // scan chunk length (steps per LDS buffer)

typedef __bf16 bf16x8 __attribute__((ext_vector_type(8)));
typedef float f32x4 __attribute__((ext_vector_type(4)));

__device__ __forceinline__ float sigmoidf_(float x) { return 1.f / (1.f + __expf(-x)); }

// async global -> LDS DMA (gfx950). LDS dst is wave-uniform; lane i's data
// lands at dst + i*size. Global src is a normal per-lane address.
__device__ __forceinline__ void gl2lds16(const float* g, void* l) {
    __builtin_amdgcn_global_load_lds((const __attribute__((address_space(1))) void*)g,
                                     (__attribute__((address_space(3))) void*)l, 16, 0, 0);
}
__device__ __forceinline__ void gl2lds4(const float* g, void* l) {
    __builtin_amdgcn_global_load_lds((const __attribute__((address_space(1))) void*)g,
                                     (__attribute__((address_space(3))) void*)l, 4, 0, 0);
}

// ---------------------------------------------------------------------------
// bf16-MFMA GEMM: C[M,N] = A[M,K] @ B[K,N], fp32 in/out, bf16 compute.
// (unchanged from round 3 — verified correct)
// ---------------------------------------------------------------------------
__global__ __launch_bounds__(256) void gemm_bf16(const float* __restrict__ A,
                                                 const float* __restrict__ B,
                                                 float* __restrict__ C,
                                                 int M, int N, int K) {
    constexpr int LW = 40;
    __shared__ __align__(16) __bf16 As[128 * LW];
    __shared__ __align__(16) __bf16 Bs[128 * LW];
    const int tid = threadIdx.x;
    const int lane = tid & 63;
    const int wave = tid >> 6;
    const int wm = (wave >> 1) * 64, wn = (wave & 1) * 64;
    const int bm = blockIdx.y * 128, bn = blockIdx.x * 128;
    const int l15 = lane & 15, quad = lane >> 4;

    const int ar = tid >> 1, akc = (tid & 1) * 16;
    const int bcol = tid & 127, bk0 = (tid >> 7) * 16;

    f32x4 acc[4][4];
#pragma unroll
    for (int i = 0; i < 4; i++)
#pragma unroll
        for (int j = 0; j < 4; j++) acc[i][j] = (f32x4){0.f, 0.f, 0.f, 0.f};

    for (int kb = 0; kb < K; kb += 32) {
        float av[16];
        const float* ap = A + (size_t)(bm + ar) * K + kb + akc;
#pragma unroll
        for (int p = 0; p < 4; p++) {
            float4 t = *(const float4*)(ap + 4 * p);
            av[4 * p + 0] = t.x; av[4 * p + 1] = t.y; av[4 * p + 2] = t.z; av[4 * p + 3] = t.w;
        }
        float bv[16];
        const float* bp = B + (size_t)(kb + bk0) * N + bn + bcol;
#pragma unroll
        for (int p = 0; p < 16; p++) bv[p] = bp[(size_t)p * N];

        __syncthreads();
        bf16x8 w0, w1, u0, u1;
#pragma unroll
        for (int p = 0; p < 8; p++) {
            w0[p] = (__bf16)av[p]; w1[p] = (__bf16)av[8 + p];
            u0[p] = (__bf16)bv[p]; u1[p] = (__bf16)bv[8 + p];
        }
        *(bf16x8*)&As[ar * LW + akc] = w0;
        *(bf16x8*)&As[ar * LW + akc + 8] = w1;
        *(bf16x8*)&Bs[bcol * LW + bk0] = u0;
        *(bf16x8*)&Bs[bcol * LW + bk0 + 8] = u1;
        __syncthreads();

        bf16x8 af[4], bfr[4];
#pragma unroll
        for (int i = 0; i < 4; i++)
            af[i] = *(const bf16x8*)&As[(wm + i * 16 + l15) * LW + quad * 8];
#pragma unroll
        for (int j = 0; j < 4; j++)
            bfr[j] = *(const bf16x8*)&Bs[(wn + j * 16 + l15) * LW + quad * 8];
#pragma unroll
        for (int i = 0; i < 4; i++)
#pragma unroll
            for (int j = 0; j < 4; j++)
                acc[i][j] = __builtin_amdgcn_mfma_f32_16x16x32_bf16(af[i], bfr[j], acc[i][j], 0, 0, 0);
    }

#pragma unroll
    for (int i = 0; i < 4; i++) {
#pragma unroll
        for (int r = 0; r < 4; r++) {
            const int row = bm + wm + i * 16 + quad * 4 + r;
            float* cp = C + (size_t)row * N + bn + wn + l15;
#pragma unroll
            for (int j = 0; j < 4; j++) cp[j * 16] = acc[i][j][r];
        }
    }
}

// ---------------------------------------------------------------------------
// Generic fp32 tiled GEMM (used for gate = g1 @ Wg2, K=64).
// ---------------------------------------------------------------------------
__global__ __launch_bounds__(256) void gemm_f32(const float* __restrict__ A,
                                                const float* __restrict__ B,
                                                float* __restrict__ C,
                                                int M, int N, int K) {
    __shared__ float As[16][128];
    __shared__ float Bs[16][128];
    const int tid = threadIdx.x;
    const int bm = blockIdx.y * 128;
    const int bn = blockIdx.x * 128;
    const int tx = tid & 15, ty = tid >> 4;
    const int arow = tid >> 1, ak0 = (tid & 1) * 8;
    const int brow = tid >> 4, bn0 = (tid & 15) * 8;

    float acc[8][8];
#pragma unroll
    for (int i = 0; i < 8; i++)
#pragma unroll
        for (int j = 0; j < 8; j++) acc[i][j] = 0.f;

    for (int kb = 0; kb < K; kb += 16) {
        const float* ap = A + (size_t)(bm + arow) * K + kb + ak0;
        float4 a0 = *(const float4*)(ap);
        float4 a1 = *(const float4*)(ap + 4);
        const int gn = bn + bn0;
        float4 b0 = make_float4(0.f, 0.f, 0.f, 0.f), b1 = b0;
        if (gn < N) {
            const float* bp = B + (size_t)(kb + brow) * N + gn;
            b0 = *(const float4*)(bp);
            b1 = *(const float4*)(bp + 4);
        }
        __syncthreads();
        As[ak0 + 0][arow] = a0.x; As[ak0 + 1][arow] = a0.y;
        As[ak0 + 2][arow] = a0.z; As[ak0 + 3][arow] = a0.w;
        As[ak0 + 4][arow] = a1.x; As[ak0 + 5][arow] = a1.y;
        As[ak0 + 6][arow] = a1.z; As[ak0 + 7][arow] = a1.w;
        *(float4*)&Bs[brow][bn0] = b0;
        *(float4*)&Bs[brow][bn0 + 4] = b1;
        __syncthreads();
#pragma unroll
        for (int kk = 0; kk < 16; kk++) {
            float4 x0 = *(const float4*)&As[kk][ty * 8];
            float4 x1 = *(const float4*)&As[kk][ty * 8 + 4];
            float4 y0 = *(const float4*)&Bs[kk][tx * 8];
            float4 y1 = *(const float4*)&Bs[kk][tx * 8 + 4];
            float xa[8] = {x0.x, x0.y, x0.z, x0.w, x1.x, x1.y, x1.z, x1.w};
            float yb[8] = {y0.x, y0.y, y0.z, y0.w, y1.x, y1.y, y1.z, y1.w};
#pragma unroll
            for (int i = 0; i < 8; i++)
#pragma unroll
                for (int j = 0; j < 8; j++) acc[i][j] += xa[i] * yb[j];
        }
    }
    const int cn = bn + tx * 8;
    if (cn < N) {
#pragma unroll
        for (int i = 0; i < 8; i++) {
            float* cp = C + (size_t)(bm + ty * 8 + i) * N + cn;
            *(float4*)cp = make_float4(acc[i][0], acc[i][1], acc[i][2], acc[i][3]);
            *(float4*)(cp + 4) = make_float4(acc[i][4], acc[i][5], acc[i][6], acc[i][7]);
        }
    }
}

// ---------------------------------------------------------------------------
// Fused skinny projections: [graw|fraw|g1] = x @ [Wgamma|Wf|Wg1]  (96 cols).
// Block: 16 rows x all 96 cols; thread (row = tid>>4, colgroup = tid&15) owns
// 6 cols. x staged per 64-k chunk in LDS (padded, broadcast reads). 256 blocks.
// ---------------------------------------------------------------------------
__global__ __launch_bounds__(256) void proj96(const float* __restrict__ x,
                                              const float* __restrict__ Wgm,
                                              const float* __restrict__ Wf,
                                              const float* __restrict__ Wg1,
                                              float* __restrict__ graw,
                                              float* __restrict__ fraw,
                                              float* __restrict__ g1) {
    __shared__ float xs[16][65];
    const int tid = threadIdx.x;
    const int row0 = blockIdx.x * 16;
    const int r = tid >> 4;       // 0..15
    const int cg = tid & 15;      // 0..15

    // my 6 columns: precompute (weight ptr, stride) per column
    const float* wp[6];
    int ws[6];
#pragma unroll
    for (int j = 0; j < 6; j++) {
        const int c = cg * 6 + j;  // 0..95
        if (c < 16)      { wp[j] = Wgm + c;        ws[j] = 16; }
        else if (c < 32) { wp[j] = Wf + (c - 16);  ws[j] = 16; }
        else             { wp[j] = Wg1 + (c - 32); ws[j] = 64; }
    }

    float acc[6];
#pragma unroll
    for (int j = 0; j < 6; j++) acc[j] = 0.f;

    const int sr = tid >> 4, sc = (tid & 15) * 4;  // staging: row sr, 4 floats at sc
    for (int kc = 0; kc < DD; kc += 64) {
        float4 t = *(const float4*)(x + (size_t)(row0 + sr) * DD + kc + sc);
        __syncthreads();
        xs[sr][sc + 0] = t.x; xs[sr][sc + 1] = t.y; xs[sr][sc + 2] = t.z; xs[sr][sc + 3] = t.w;
        __syncthreads();
#pragma unroll 8
        for (int kk = 0; kk < 64; kk++) {
            const float xv = xs[r][kk];
#pragma unroll
            for (int j = 0; j < 6; j++) acc[j] += xv * wp[j][(size_t)(kc + kk) * ws[j]];
        }
    }

#pragma unroll
    for (int j = 0; j < 6; j++) {
        const int c = cg * 6 + j;
        const int gr = row0 + r;
        if (c < 16)      graw[(size_t)gr * 16 + c] = acc[j];
        else if (c < 32) fraw[(size_t)gr * 16 + (c - 16)] = acc[j];
        else             g1[(size_t)gr * 64 + (c - 32)] = acc[j];
    }
}

// ---------------------------------------------------------------------------
// Post-projection elementwise. One wave per (row, head). (unchanged)
// ---------------------------------------------------------------------------
__global__ __launch_bounds__(256) void prep_kernel(float* qb, float* kb, float* vb,
                                                   const float* __restrict__ fraw,
                                                   const float* __restrict__ graw,
                                                   float* lfb, float* csb) {
    const int tid = threadIdx.x;
    const int wav = tid >> 6, lane = tid & 63;
    const int gid = blockIdx.x * 4 + wav;  // (r,h)
    const int r = gid >> 4, h = gid & 15;
    const size_t idx = (size_t)r * DD + (size_t)h * HD + lane;

    float xq = qb[idx], xk = kb[idx], xv = vb[idx];
    float q = xq * sigmoidf_(xq);
    float v = xv * sigmoidf_(xv);
    float kk = xk * sigmoidf_(xk);
    float ss = kk * kk;
#pragma unroll
    for (int m = 1; m <= 32; m <<= 1) ss += __shfl_xor(ss, m);
    float norm = fmaxf(sqrtf(ss), 1e-12f);
    float kn = kk / norm;

    float f = fraw[(size_t)r * HH + h];
    float sig = sigmoidf_(f);                               // lambda
    float gm = -sigmoidf_(graw[(size_t)r * HH + h]);        // gamma

    qb[idx] = q;
    vb[idx] = v;
    kb[idx] = kn;
    if (lane == 0) {
        lfb[(size_t)r * HH + h] = sig;
        csb[(size_t)r * HH + h] = gm * sig * sig;
    }
}

// ---------------------------------------------------------------------------
// Sequential delta-rule scan, LDS double-buffered in CH-step chunks staged by
// async global_load_lds. One wave per (b,h, v-slice of 16): 128 blocks x 64.
// Lane = (kq in 0..3) x (vloc in 0..15). S[k][v] in 16 VGPRs/lane.
//   pu = k.S ; u = c*pu + v ; S = lam*S + k u ; o = q.S
// Inner loop: depth-2 register pipeline over ds_read (lgkmcnt is fine-grained).
// ---------------------------------------------------------------------------
__global__ __launch_bounds__(64) void scan_kernel(const float* __restrict__ qb,
                                                  const float* __restrict__ kb,
                                                  const float* __restrict__ vb,
                                                  const float* __restrict__ lfb,
                                                  const float* __restrict__ csb,
                                                  __bf16* __restrict__ obh) {
    // NO padding: global_load_lds lands lane i at base + i*16 (contiguous).
    __shared__ __align__(16) float ks[2][CH][64];
    __shared__ __align__(16) float qs[2][CH][64];
    __shared__ __align__(16) float vs[2][CH][16];
    __shared__ __align__(16) float ms[2][64];  // [t]=lambda, [32+t]=c

    const int bx = blockIdx.x;
    const int bh = bx >> 2, wslice = bx & 3;
    const int b = bh >> 4, h = bh & 15;
    const int lane = threadIdx.x;
    const int kq = lane >> 4, vloc = lane & 15;
    const size_t base0 = (size_t)(b * NN) * DD + (size_t)h * HD;
    const size_t lf0 = (size_t)(b * NN) * HH + h;

    // staging lane decompositions
    const int rk = lane >> 4, ck = (lane & 15) * 4;  // k/q: 4 rows/instr
    const int rv = lane >> 2, cv = (lane & 3) * 4;   // v:  16 rows/instr

    float S[16];
#pragma unroll
    for (int i = 0; i < 16; i++) S[i] = 0.f;

    auto stage = [&](int c, int bsel) {
        const int t0 = c * CH;
#pragma unroll
        for (int r0 = 0; r0 < CH; r0 += 4) {
            gl2lds16(kb + base0 + (size_t)(t0 + r0 + rk) * DD + ck, &ks[bsel][r0][0]);
            gl2lds16(qb + base0 + (size_t)(t0 + r0 + rk) * DD + ck, &qs[bsel][r0][0]);
        }
#pragma unroll
        for (int r0 = 0; r0 < CH; r0 += 16) {
            gl2lds16(vb + base0 + (size_t)(t0 + r0 + rv) * DD + wslice * 16 + cv,
                     &vs[bsel][r0][0]);
        }
        // lanes 0..31: lambda[t0+lane]; lanes 32..63: c[t0+lane-32]
        const float* mg = (lane < 32) ? (lfb + lf0 + (size_t)(t0 + lane) * HH)
                                      : (csb + lf0 + (size_t)(t0 + (lane - 32)) * HH);
        gl2lds4(mg, &ms[bsel][0]);
    };

    stage(0, 0);
    __syncthreads();

    for (int c = 0; c < NN / CH; c++) {
        const int cur = c & 1;
        if (c + 1 < NN / CH) stage(c + 1, cur ^ 1);

        const float* kS = &ks[cur][0][0];
        const float* qS = &qs[cur][0][0];
        const float* vS = &vs[cur][0][0];
        const float* mS = &ms[cur][0];
        const int t0 = c * CH;

        float4 KF[2][4], QF[2][4];
        float VF[2], LMF[2], CSF[2];
        // preload step 0 into slot 0
        {
            const float4* kp = (const float4*)(kS + kq * 16);
            const float4* qp = (const float4*)(qS + kq * 16);
#pragma unroll
            for (int j = 0; j < 4; j++) { KF[0][j] = kp[j]; QF[0][j] = qp[j]; }
            VF[0] = vS[vloc];
            LMF[0] = mS[0];
            CSF[0] = mS[32];
        }

        for (int tb = 0; tb < CH; tb += 8) {
#pragma unroll
            for (int i = 0; i < 8; i++) {
                const int tt = tb + i;
                const int cs = i & 1, ns = cs ^ 1;
                // prefetch step tt+1 into the other slot (clamp at CH-1)
                const int tn = (tt + 1 < CH) ? tt + 1 : CH - 1;
                {
                    const float4* kp = (const float4*)(kS + tn * 64 + kq * 16);
                    const float4* qp = (const float4*)(qS + tn * 64 + kq * 16);
#pragma unroll
                    for (int j = 0; j < 4; j++) { KF[ns][j] = kp[j]; QF[ns][j] = qp[j]; }
                    VF[ns] = vS[tn * 16 + vloc];
                    LMF[ns] = mS[tn];
                    CSF[ns] = mS[32 + tn];
                }
                // compute step tt from slot cs
                const float lam = LMF[cs];
                float pj[4];
#pragma unroll
                for (int j = 0; j < 4; j++) {
                    pj[j] = KF[cs][j].x * S[4 * j + 0] + KF[cs][j].y * S[4 * j + 1] +
                            KF[cs][j].z * S[4 * j + 2] + KF[cs][j].w * S[4 * j + 3];
                }
                float pu = (pj[0] + pj[1]) + (pj[2] + pj[3]);
                pu += __shfl_xor(pu, 16);
                pu += __shfl_xor(pu, 32);
                const float u = CSF[cs] * pu + VF[cs];
                float oj[4];
#pragma unroll
                for (int j = 0; j < 4; j++) {
                    float s0 = lam * S[4 * j + 0] + KF[cs][j].x * u;
                    float s1 = lam * S[4 * j + 1] + KF[cs][j].y * u;
                    float s2 = lam * S[4 * j + 2] + KF[cs][j].z * u;
                    float s3 = lam * S[4 * j + 3] + KF[cs][j].w * u;
                    S[4 * j + 0] = s0; S[4 * j + 1] = s1;
                    S[4 * j + 2] = s2; S[4 * j + 3] = s3;
                    oj[j] = QF[cs][j].x * s0 + QF[cs][j].y * s1 +
                            QF[cs][j].z * s2 + QF[cs][j].w * s3;
                }
                float po = (oj[0] + oj[1]) + (oj[2] + oj[3]);
                po += __shfl_xor(po, 16);
                po += __shfl_xor(po, 32);
                if (lane < 16)
                    obh[base0 + (size_t)(t0 + tt) * DD + wslice * 16 + lane] = (__bf16)po;
            }
        }
        __syncthreads();  // all reads of buf[cur] done; staged buf[!cur] drained
    }
}

// ---------------------------------------------------------------------------
// outp = LayerNorm(o * sigmoid(gatep)) * norm_w. o is bf16, result fp32.
// ---------------------------------------------------------------------------
__global__ __launch_bounds__(256) void gate_ln_kernel(const __bf16* __restrict__ obh,
                                                      const float* __restrict__ gatep,
                                                      const float* __restrict__ nw,
                                                      float* __restrict__ outp) {
    const int r = blockIdx.x, tid = threadIdx.x;
    const int wav = tid >> 6, lane = tid & 63;
    __shared__ float red[8];
    const size_t rb = (size_t)r * DD;

    float vals[4];
    float s = 0.f;
#pragma unroll
    for (int p = 0; p < 4; p++) {
        const int j = tid + 256 * p;
        float xg = (float)obh[rb + j] * sigmoidf_(gatep[rb + j]);
        vals[p] = xg;
        s += xg;
    }
#pragma unroll
    for (int m = 1; m <= 32; m <<= 1) s += __shfl_xor(s, m);
    if (lane == 0) red[wav] = s;
    __syncthreads();
    const float mu = (red[0] + red[1] + red[2] + red[3]) * (1.f / 1024.f);

    float s2 = 0.f;
#pragma unroll
    for (int p = 0; p < 4; p++) { float d = vals[p] - mu; s2 += d * d; }
#pragma unroll
    for (int m = 1; m <= 32; m <<= 1) s2 += __shfl_xor(s2, m);
    if (lane == 0) red[4 + wav] = s2;
    __syncthreads();
    const float var = (red[4] + red[5] + red[6] + red[7]) * (1.f / 1024.f);
    const float rs = rsqrtf(var + 1e-5f);

#pragma unroll
    for (int p = 0; p < 4; p++) {
        const int j = tid + 256 * p;
        outp[rb + j] = (vals[p] - mu) * rs * nw[j];
    }
}

// ---------------------------------------------------------------------------
extern "C" void kernel_launch(void* const* d_in, const int* in_sizes, int n_in,
                              void* d_out, int out_size, void* d_ws, size_t ws_size,
                              hipStream_t stream) {
    const float* x   = (const float*)d_in[0];
    const float* Wq  = (const float*)d_in[1];
    const float* Wk  = (const float*)d_in[2];
    const float* Wv  = (const float*)d_in[3];
    const float* Wgm = (const float*)d_in[4];  // Wgamma
    const float* Wf  = (const float*)d_in[5];
    const float* Wg1 = (const float*)d_in[6];
    const float* Wg2 = (const float*)d_in[7];
    const float* Wo  = (const float*)d_in[8];
    const float* nw  = (const float*)d_in[9];
    float* out = (float*)d_out;

    float* w = (float*)d_ws;
    float* qb    = w;                   // 4096x1024 f32 (q; later LN output)
    float* kb    = qb + 4194304;
    float* vb    = kb + 4194304;
    float* gatep = vb + 4194304;
    float* fraw  = gatep + 4194304;     // 4096x16
    float* graw  = fraw + 65536;        // 4096x16
    float* g1    = graw + 65536;        // 4096x64
    float* lfb   = g1 + 262144;         // 4096x16 (lambda)
    float* csb   = lfb + 65536;         // 4096x16 (gamma*lambda^2)
    __bf16* obh  = (__bf16*)(csb + 65536);  // 4096x1024 bf16 scan output

    dim3 blk(256);
    gemm_bf16<<<dim3(8, 32), blk, 0, stream>>>(x, Wq, qb, RR, DD, DD);
    gemm_bf16<<<dim3(8, 32), blk, 0, stream>>>(x, Wk, kb, RR, DD, DD);
    gemm_bf16<<<dim3(8, 32), blk, 0, stream>>>(x, Wv, vb, RR, DD, DD);
    proj96<<<RR / 16, blk, 0, stream>>>(x, Wgm, Wf, Wg1, graw, fraw, g1);
    gemm_f32<<<dim3(8, 32), blk, 0, stream>>>(g1, Wg2, gatep, RR, DD, HD);
    prep_kernel<<<RR * HH / 4, blk, 0, stream>>>(qb, kb, vb, fraw, graw, lfb, csb);
    scan_kernel<<<128, 64, 0, stream>>>(qb, kb, vb, lfb, csb, obh);
    gate_ln_kernel<<<RR, blk, 0, stream>>>(obh, gatep, nw, qb);
    gemm_bf16<<<dim3(8, 32), blk, 0, stream>>>(qb, Wo, out, RR, DD, DD);
}